// Round 1
// baseline (1914.851 us; speedup 1.0000x reference)
//
#include <hip/hip_runtime.h>
#include <math.h>

// ---------------------------------------------------------------------------
// TrafficGNN: 2-layer GCN + BN + ReLU + log_softmax.  All fp32.
// Inputs: x[N,128], edge_index[2,E] (int), edge_weight[E],
//         W1[128,128], b1[128], gamma[128], beta[128], W2[128,64], b2[64]
// Output: log_softmax(conv2(relu(bn(conv1(x)))))  [N,64]
// ---------------------------------------------------------------------------

__device__ __forceinline__ void atomAddF(float* p, float v) {
    __hip_atomic_fetch_add(p, v, __ATOMIC_RELAXED, __HIP_MEMORY_SCOPE_AGENT);
}

// deg init (self-loop weight 1.0) + zero BN accumulators
__global__ void k_init(float* __restrict__ deg, float* __restrict__ bn, int n) {
    int i = blockIdx.x * 256 + threadIdx.x;
    if (i < n) deg[i] = 1.0f;
    if (i < 256) bn[i] = 0.0f;   // bn[0..127]=sum, bn[128..255]=sumsq
}

// deg[col[e]] += ew[e]
__global__ void k_deg(const int* __restrict__ col, const float* __restrict__ ew,
                      float* __restrict__ deg, int e) {
    int i = blockIdx.x * 256 + threadIdx.x;
    if (i < e) atomAddF(&deg[col[i]], ew[i]);
}

// dinv = deg>0 ? rsqrt(deg) : 0   (in place)
__global__ void k_dinv(float* __restrict__ deg, int n) {
    int i = blockIdx.x * 256 + threadIdx.x;
    if (i < n) { float d = deg[i]; deg[i] = d > 0.f ? rsqrtf(d) : 0.f; }
}

// H[n,M] = X'[n,128] @ W[128,M], where X' = BN?relu(X*scale+shift):X
// Block: 128 rows x M cols, 256 threads as 16(col-groups) x 16(row-groups),
// each thread 8 rows x (M/16) cols.
template<int M, bool BN>
__global__ __launch_bounds__(256)
void k_gemm(const float* __restrict__ X, const float* __restrict__ W,
            const float* __restrict__ scale, const float* __restrict__ shift,
            float* __restrict__ H, int n)
{
    constexpr int K = 128;
    constexpr int TK = 32;
    constexpr int CPT = M / 16;          // 8 (M=128) or 4 (M=64)
    __shared__ float xs[128][TK + 1];    // +1 pad: kills 4-way bank conflict
    __shared__ float wsm[TK][M];

    const int t  = threadIdx.x;
    const int cg = t & 15;
    const int rg = t >> 4;
    const long long block_row = (long long)blockIdx.x * 128;

    float acc[8][CPT];
#pragma unroll
    for (int r = 0; r < 8; ++r)
#pragma unroll
        for (int c = 0; c < CPT; ++c) acc[r][c] = 0.f;

    const int xr0 = t >> 3;          // 0..31
    const int xc0 = (t & 7) * 4;     // 0..28

    for (int kp = 0; kp < K; kp += TK) {
        // X panel (with fused BN+ReLU for layer 2)
#pragma unroll
        for (int i = 0; i < 4; ++i) {
            int r = xr0 + i * 32;
            long long gr = block_row + r;
            float4 v = make_float4(0.f, 0.f, 0.f, 0.f);
            if (gr < n) v = *(const float4*)(X + gr * K + kp + xc0);
            if (BN) {
                float4 sc = *(const float4*)(scale + kp + xc0);
                float4 sh = *(const float4*)(shift + kp + xc0);
                v.x = fmaxf(0.f, fmaf(v.x, sc.x, sh.x));
                v.y = fmaxf(0.f, fmaf(v.y, sc.y, sh.y));
                v.z = fmaxf(0.f, fmaf(v.z, sc.z, sh.z));
                v.w = fmaxf(0.f, fmaf(v.w, sc.w, sh.w));
            }
            xs[r][xc0 + 0] = v.x; xs[r][xc0 + 1] = v.y;
            xs[r][xc0 + 2] = v.z; xs[r][xc0 + 3] = v.w;
        }
        // W panel
        constexpr int WL = (TK * M) / (256 * 4);
#pragma unroll
        for (int j = 0; j < WL; ++j) {
            int idx = t + j * 256;
            int r  = idx / (M / 4);
            int c4 = (idx % (M / 4)) * 4;
            *(float4*)(&wsm[r][c4]) = *(const float4*)(W + (long long)(kp + r) * M + c4);
        }
        __syncthreads();
#pragma unroll
        for (int k = 0; k < TK; ++k) {
            float xv[8], wv[CPT];
#pragma unroll
            for (int r = 0; r < 8; ++r) xv[r] = xs[rg * 8 + r][k];
#pragma unroll
            for (int c = 0; c < CPT; ++c) wv[c] = wsm[k][cg * CPT + c];
#pragma unroll
            for (int r = 0; r < 8; ++r)
#pragma unroll
                for (int c = 0; c < CPT; ++c)
                    acc[r][c] = fmaf(xv[r], wv[c], acc[r][c]);
        }
        __syncthreads();
    }
#pragma unroll
    for (int r = 0; r < 8; ++r) {
        long long gr = block_row + rg * 8 + r;
        if (gr < n) {
#pragma unroll
            for (int c = 0; c < CPT; c += 4) {
                float4 v = make_float4(acc[r][c], acc[r][c + 1], acc[r][c + 2], acc[r][c + 3]);
                *(float4*)(H + gr * M + cg * CPT + c) = v;
            }
        }
    }
}

// out[i,f] = bias[f] + h[i,f] * dinv[i]^2    (self-loop message + bias)
template<int F>
__global__ void k_agg_init(const float* __restrict__ h, const float* __restrict__ dinv,
                           const float* __restrict__ bias, float* __restrict__ out,
                           int n)
{
    long long i4 = (long long)blockIdx.x * blockDim.x + threadIdx.x;
    long long total = (long long)n * (F / 4);
    if (i4 >= total) return;
    int node = (int)(i4 / (F / 4));
    int c4   = (int)(i4 % (F / 4)) * 4;
    float di = dinv[node];
    float s  = di * di;
    float4 hv = *(const float4*)(h + i4 * 4);
    float4 bv = *(const float4*)(bias + c4);
    float4 o  = make_float4(fmaf(hv.x, s, bv.x), fmaf(hv.y, s, bv.y),
                            fmaf(hv.z, s, bv.z), fmaf(hv.w, s, bv.w));
    *(float4*)(out + i4 * 4) = o;
}

// one wave per edge: out[col] += h[row] * (dinv[row]*ew*dinv[col])
template<int F>
__global__ __launch_bounds__(256)
void k_edge(const int* __restrict__ row, const int* __restrict__ col,
            const float* __restrict__ ew, const float* __restrict__ dinv,
            const float* __restrict__ h, float* __restrict__ out, int e_cnt)
{
    int lane = threadIdx.x & 63;
    int wid  = (blockIdx.x * 256 + threadIdx.x) >> 6;
    int nw   = (gridDim.x * 256) >> 6;
    for (int e = wid; e < e_cnt; e += nw) {
        int r = row[e], c = col[e];
        float w = ew[e] * dinv[r] * dinv[c];
        if (F == 128) {
            float2 hv = *(const float2*)(h + (size_t)r * 128 + lane * 2);
            atomAddF(out + (size_t)c * 128 + lane * 2,     hv.x * w);
            atomAddF(out + (size_t)c * 128 + lane * 2 + 1, hv.y * w);
        } else {
            float hv = h[(size_t)r * 64 + lane];
            atomAddF(out + (size_t)c * 64 + lane, hv * w);
        }
    }
}

// per-feature sum & sumsq over nodes (128 feats)
__global__ __launch_bounds__(256)
void k_bn_stats(const float* __restrict__ a, float* __restrict__ sums,
                float* __restrict__ sumsq, int n)
{
    int f = threadIdx.x & 127;
    int r0 = blockIdx.x * 2 + (threadIdx.x >> 7);
    float s = 0.f, q = 0.f;
    for (int r = r0; r < n; r += gridDim.x * 2) {
        float v = a[(size_t)r * 128 + f];
        s += v; q += v * v;
    }
    __shared__ float ls[256], lq[256];
    ls[threadIdx.x] = s; lq[threadIdx.x] = q;
    __syncthreads();
    if (threadIdx.x < 128) {
        atomAddF(&sums[f],  ls[threadIdx.x] + ls[threadIdx.x + 128]);
        atomAddF(&sumsq[f], lq[threadIdx.x] + lq[threadIdx.x + 128]);
    }
}

// scale = gamma*rstd ; shift = beta - mu*scale
__global__ void k_bn_final(const float* __restrict__ bn, const float* __restrict__ gamma,
                           const float* __restrict__ beta, float* __restrict__ scale,
                           float* __restrict__ shift, int n)
{
    int f = threadIdx.x;
    if (f < 128) {
        float inv_n = 1.0f / (float)n;
        float mu  = bn[f] * inv_n;
        float var = bn[128 + f] * inv_n - mu * mu;
        float rstd = rsqrtf(var + 1e-5f);
        float sc = gamma[f] * rstd;
        scale[f] = sc;
        shift[f] = beta[f] - mu * sc;
    }
}

// in-place log_softmax over 64 features; one wave per node
__global__ __launch_bounds__(256)
void k_lsm(float* __restrict__ out, int n)
{
    int lane = threadIdx.x & 63;
    int wid  = (blockIdx.x * 256 + threadIdx.x) >> 6;
    if (wid >= n) return;
    float v = out[(size_t)wid * 64 + lane];
    float m = v;
#pragma unroll
    for (int off = 32; off > 0; off >>= 1) m = fmaxf(m, __shfl_xor(m, off, 64));
    float ex = expf(v - m);
    float s = ex;
#pragma unroll
    for (int off = 32; off > 0; off >>= 1) s += __shfl_xor(s, off, 64);
    out[(size_t)wid * 64 + lane] = v - m - logf(s);
}

extern "C" void kernel_launch(void* const* d_in, const int* in_sizes, int n_in,
                              void* d_out, int out_size, void* d_ws, size_t ws_size,
                              hipStream_t stream)
{
    const float* x     = (const float*)d_in[0];
    const int*   ei    = (const int*)  d_in[1];
    const float* ew    = (const float*)d_in[2];
    const float* W1    = (const float*)d_in[3];
    const float* b1    = (const float*)d_in[4];
    const float* gamma = (const float*)d_in[5];
    const float* beta  = (const float*)d_in[6];
    const float* W2    = (const float*)d_in[7];
    const float* b2    = (const float*)d_in[8];

    const int n = in_sizes[0] / 128;   // 100000
    const int e = in_sizes[2];         // 1600000
    const int* row = ei;               // edge_index[0]
    const int* col = ei + e;           // edge_index[1]

    // workspace layout (floats): dinv[n] | h1[n*128] (aliased by h2[n*64]) |
    //                            agg1[n*128] | bn[256] | scale[128] | shift[128]
    float* ws    = (float*)d_ws;
    float* dinv  = ws;
    float* h1    = dinv + n;
    float* agg1  = h1 + (size_t)n * 128;
    float* bn    = agg1 + (size_t)n * 128;
    float* scale = bn + 256;
    float* shift = scale + 128;
    float* h2    = h1;                 // h1 dead after first edge pass
    float* outp  = (float*)d_out;

    const int nb_n = (n + 255) / 256;

    k_init<<<nb_n, 256, 0, stream>>>(dinv, bn, n);
    k_deg<<<(e + 255) / 256, 256, 0, stream>>>(col, ew, dinv, e);
    k_dinv<<<nb_n, 256, 0, stream>>>(dinv, n);

    // ---- layer 1: h1 = x @ W1 ; agg1 = scatter(h1) + b1 ----
    k_gemm<128, false><<<(n + 127) / 128, 256, 0, stream>>>(x, W1, nullptr, nullptr, h1, n);
    {
        long long tot = (long long)n * 32;            // n*128/4 float4s
        k_agg_init<128><<<(int)((tot + 255) / 256), 256, 0, stream>>>(h1, dinv, b1, agg1, n);
    }
    k_edge<128><<<8192, 256, 0, stream>>>(row, col, ew, dinv, h1, agg1, e);

    // ---- batchnorm stats -> scale/shift ----
    k_bn_stats<<<256, 256, 0, stream>>>(agg1, bn, bn + 128, n);
    k_bn_final<<<1, 128, 0, stream>>>(bn, gamma, beta, scale, shift, n);

    // ---- layer 2: h2 = relu(bn(agg1)) @ W2 ; out = scatter(h2) + b2 ----
    k_gemm<64, true><<<(n + 127) / 128, 256, 0, stream>>>(agg1, W2, scale, shift, h2, n);
    {
        long long tot = (long long)n * 16;            // n*64/4 float4s
        k_agg_init<64><<<(int)((tot + 255) / 256), 256, 0, stream>>>(h2, dinv, b2, outp, n);
    }
    k_edge<64><<<8192, 256, 0, stream>>>(row, col, ew, dinv, h2, outp, e);

    // ---- log_softmax in place ----
    k_lsm<<<(n + 3) / 4, 256, 0, stream>>>(outp, n);
}

// Round 3
// 619.552 us; speedup vs baseline: 3.0907x; 3.0907x over previous
//
#include <hip/hip_runtime.h>
#include <math.h>

// ---------------------------------------------------------------------------
// TrafficGNN: 2-layer GCN + BN + ReLU + log_softmax.  All fp32.
// Round 3: fix k_gather launch geometry (wave-per-node needs n*64 threads,
// i.e. (n+3)/4 blocks of 256 — Round 2 launched 1/16 of that).
// ---------------------------------------------------------------------------

__device__ __forceinline__ void atomAddF(float* p, float v) {
    __hip_atomic_fetch_add(p, v, __ATOMIC_RELAXED, __HIP_MEMORY_SCOPE_AGENT);
}

// deg init (self-loop weight 1.0) + zero edge counters + zero BN accumulators
__global__ void k_init(float* __restrict__ deg, int* __restrict__ cnt,
                       float* __restrict__ bn, int n) {
    int i = blockIdx.x * 256 + threadIdx.x;
    if (i < n) { deg[i] = 1.0f; cnt[i] = 0; }
    if (i < 256) bn[i] = 0.0f;   // bn[0..127]=sum, bn[128..255]=sumsq
}

// deg[col[e]] += ew[e]  and  cnt[col[e]] += 1
__global__ void k_deg_cnt(const int* __restrict__ col, const float* __restrict__ ew,
                          float* __restrict__ deg, int* __restrict__ cnt, int e) {
    int i = blockIdx.x * 256 + threadIdx.x;
    if (i < e) {
        int c = col[i];
        atomAddF(&deg[c], ew[i]);
        atomicAdd(&cnt[c], 1);
    }
}

// dinv = deg>0 ? rsqrt(deg) : 0   (in place)
__global__ void k_dinv(float* __restrict__ deg, int n) {
    int i = blockIdx.x * 256 + threadIdx.x;
    if (i < n) { float d = deg[i]; deg[i] = d > 0.f ? rsqrtf(d) : 0.f; }
}

// ---- exclusive scan of cnt[n] -> ptr[n+1], plus a mutable copy cur[n] ----

__global__ __launch_bounds__(256)
void k_scanA(const int* __restrict__ cnt, int* __restrict__ bsum, int n) {
    __shared__ int ls[256];
    int base = blockIdx.x * 1024 + threadIdx.x * 4;
    int s = 0;
#pragma unroll
    for (int k = 0; k < 4; ++k) { int i = base + k; if (i < n) s += cnt[i]; }
    ls[threadIdx.x] = s;
    __syncthreads();
    for (int d = 128; d > 0; d >>= 1) {
        if (threadIdx.x < d) ls[threadIdx.x] += ls[threadIdx.x + d];
        __syncthreads();
    }
    if (threadIdx.x == 0) bsum[blockIdx.x] = ls[0];
}

// single tiny block: exclusive scan of block sums; also writes ptr[n]=total
__global__ void k_scanB(int* __restrict__ bsum, int* __restrict__ ptr,
                        int nblk, int n) {
    if (threadIdx.x == 0) {
        int run = 0;
        for (int i = 0; i < nblk; ++i) { int v = bsum[i]; bsum[i] = run; run += v; }
        ptr[n] = run;
    }
}

__global__ __launch_bounds__(256)
void k_scanC(const int* __restrict__ cnt, const int* __restrict__ bsum,
             int* __restrict__ ptr, int* __restrict__ cur, int n) {
    __shared__ int ls[256];
    int base = blockIdx.x * 1024 + threadIdx.x * 4;
    int v[4];
#pragma unroll
    for (int k = 0; k < 4; ++k) { int i = base + k; v[k] = (i < n) ? cnt[i] : 0; }
    int t = v[0] + v[1] + v[2] + v[3];
    ls[threadIdx.x] = t;
    __syncthreads();
    // Hillis-Steele inclusive scan over 256 thread-totals
    for (int d = 1; d < 256; d <<= 1) {
        int mine = ls[threadIdx.x];
        int up   = (threadIdx.x >= d) ? ls[threadIdx.x - d] : 0;
        __syncthreads();
        ls[threadIdx.x] = mine + up;
        __syncthreads();
    }
    int off = bsum[blockIdx.x] + ls[threadIdx.x] - t;   // exclusive
    int pf = 0;
#pragma unroll
    for (int k = 0; k < 4; ++k) {
        int i = base + k;
        if (i < n) { int p = off + pf; ptr[i] = p; cur[i] = p; }
        pf += v[k];
    }
}

// fill CSR: for each edge, slot at target node; store src and full norm weight
__global__ void k_fill(const int* __restrict__ row, const int* __restrict__ col,
                       const float* __restrict__ ew, const float* __restrict__ dinv,
                       int* __restrict__ cur, int* __restrict__ csr_src,
                       float* __restrict__ csr_nrm, int e) {
    int i = blockIdx.x * 256 + threadIdx.x;
    if (i < e) {
        int r = row[i], c = col[i];
        int pos = atomicAdd(&cur[c], 1);
        csr_src[pos] = r;
        csr_nrm[pos] = ew[i] * dinv[r] * dinv[c];
    }
}

// H[n,M] = X'[n,128] @ W[128,M], where X' = BN?relu(X*scale+shift):X
template<int M, bool BN>
__global__ __launch_bounds__(256)
void k_gemm(const float* __restrict__ X, const float* __restrict__ W,
            const float* __restrict__ scale, const float* __restrict__ shift,
            float* __restrict__ H, int n)
{
    constexpr int K = 128;
    constexpr int TK = 32;
    constexpr int CPT = M / 16;          // 8 (M=128) or 4 (M=64)
    __shared__ float xs[128][TK + 1];
    __shared__ float wsm[TK][M];

    const int t  = threadIdx.x;
    const int cg = t & 15;
    const int rg = t >> 4;
    const long long block_row = (long long)blockIdx.x * 128;

    float acc[8][CPT];
#pragma unroll
    for (int r = 0; r < 8; ++r)
#pragma unroll
        for (int c = 0; c < CPT; ++c) acc[r][c] = 0.f;

    const int xr0 = t >> 3;
    const int xc0 = (t & 7) * 4;

    for (int kp = 0; kp < K; kp += TK) {
#pragma unroll
        for (int i = 0; i < 4; ++i) {
            int r = xr0 + i * 32;
            long long gr = block_row + r;
            float4 v = make_float4(0.f, 0.f, 0.f, 0.f);
            if (gr < n) v = *(const float4*)(X + gr * K + kp + xc0);
            if (BN) {
                float4 sc = *(const float4*)(scale + kp + xc0);
                float4 sh = *(const float4*)(shift + kp + xc0);
                v.x = fmaxf(0.f, fmaf(v.x, sc.x, sh.x));
                v.y = fmaxf(0.f, fmaf(v.y, sc.y, sh.y));
                v.z = fmaxf(0.f, fmaf(v.z, sc.z, sh.z));
                v.w = fmaxf(0.f, fmaf(v.w, sc.w, sh.w));
            }
            xs[r][xc0 + 0] = v.x; xs[r][xc0 + 1] = v.y;
            xs[r][xc0 + 2] = v.z; xs[r][xc0 + 3] = v.w;
        }
        constexpr int WL = (TK * M) / (256 * 4);
#pragma unroll
        for (int j = 0; j < WL; ++j) {
            int idx = t + j * 256;
            int r  = idx / (M / 4);
            int c4 = (idx % (M / 4)) * 4;
            *(float4*)(&wsm[r][c4]) = *(const float4*)(W + (long long)(kp + r) * M + c4);
        }
        __syncthreads();
#pragma unroll
        for (int k = 0; k < TK; ++k) {
            float xv[8], wv[CPT];
#pragma unroll
            for (int r = 0; r < 8; ++r) xv[r] = xs[rg * 8 + r][k];
#pragma unroll
            for (int c = 0; c < CPT; ++c) wv[c] = wsm[k][cg * CPT + c];
#pragma unroll
            for (int r = 0; r < 8; ++r)
#pragma unroll
                for (int c = 0; c < CPT; ++c)
                    acc[r][c] = fmaf(xv[r], wv[c], acc[r][c]);
        }
        __syncthreads();
    }
#pragma unroll
    for (int r = 0; r < 8; ++r) {
        long long gr = block_row + rg * 8 + r;
        if (gr < n) {
#pragma unroll
            for (int c = 0; c < CPT; c += 4) {
                float4 v = make_float4(acc[r][c], acc[r][c + 1], acc[r][c + 2], acc[r][c + 3]);
                *(float4*)(H + gr * M + cg * CPT + c) = v;
            }
        }
    }
}

// CSR gather aggregation: one wave per node; lanes cover features.
// out[i] = bias + h[i]*dinv[i]^2 + sum_{j in in(i)} h[src[j]] * nrm[j]
template<int F>
__global__ __launch_bounds__(256)
void k_gather(const int* __restrict__ ptr, const int* __restrict__ src,
              const float* __restrict__ nrm, const float* __restrict__ h,
              const float* __restrict__ dinv, const float* __restrict__ bias,
              float* __restrict__ out, int n)
{
    int lane = threadIdx.x & 63;
    int node = (blockIdx.x * 256 + threadIdx.x) >> 6;
    if (node >= n) return;
    int p0 = ptr[node], p1 = ptr[node + 1];
    float di = dinv[node];
    float s  = di * di;
    if (F == 128) {
        float2 hv = *(const float2*)(h + (size_t)node * 128 + lane * 2);
        float2 bv = *(const float2*)(bias + lane * 2);
        float2 acc = make_float2(fmaf(hv.x, s, bv.x), fmaf(hv.y, s, bv.y));
#pragma unroll 4
        for (int j = p0; j < p1; ++j) {
            int sj = src[j]; float w = nrm[j];
            float2 v = *(const float2*)(h + (size_t)sj * 128 + lane * 2);
            acc.x = fmaf(v.x, w, acc.x);
            acc.y = fmaf(v.y, w, acc.y);
        }
        *(float2*)(out + (size_t)node * 128 + lane * 2) = acc;
    } else {
        float acc = fmaf(h[(size_t)node * 64 + lane], s, bias[lane]);
#pragma unroll 4
        for (int j = p0; j < p1; ++j) {
            int sj = src[j]; float w = nrm[j];
            acc = fmaf(h[(size_t)sj * 64 + lane], w, acc);
        }
        out[(size_t)node * 64 + lane] = acc;
    }
}

// per-feature sum & sumsq over nodes (128 feats)
__global__ __launch_bounds__(256)
void k_bn_stats(const float* __restrict__ a, float* __restrict__ sums,
                float* __restrict__ sumsq, int n)
{
    int f = threadIdx.x & 127;
    int r0 = blockIdx.x * 2 + (threadIdx.x >> 7);
    float s = 0.f, q = 0.f;
    for (int r = r0; r < n; r += gridDim.x * 2) {
        float v = a[(size_t)r * 128 + f];
        s += v; q += v * v;
    }
    __shared__ float ls[256], lq[256];
    ls[threadIdx.x] = s; lq[threadIdx.x] = q;
    __syncthreads();
    if (threadIdx.x < 128) {
        atomAddF(&sums[f],  ls[threadIdx.x] + ls[threadIdx.x + 128]);
        atomAddF(&sumsq[f], lq[threadIdx.x] + lq[threadIdx.x + 128]);
    }
}

__global__ void k_bn_final(const float* __restrict__ bn, const float* __restrict__ gamma,
                           const float* __restrict__ beta, float* __restrict__ scale,
                           float* __restrict__ shift, int n)
{
    int f = threadIdx.x;
    if (f < 128) {
        float inv_n = 1.0f / (float)n;
        float mu  = bn[f] * inv_n;
        float var = bn[128 + f] * inv_n - mu * mu;
        float rstd = rsqrtf(var + 1e-5f);
        float sc = gamma[f] * rstd;
        scale[f] = sc;
        shift[f] = beta[f] - mu * sc;
    }
}

// in-place log_softmax over 64 features; one wave per node
__global__ __launch_bounds__(256)
void k_lsm(float* __restrict__ out, int n)
{
    int lane = threadIdx.x & 63;
    int wid  = (blockIdx.x * 256 + threadIdx.x) >> 6;
    if (wid >= n) return;
    float v = out[(size_t)wid * 64 + lane];
    float m = v;
#pragma unroll
    for (int off = 32; off > 0; off >>= 1) m = fmaxf(m, __shfl_xor(m, off, 64));
    float ex = expf(v - m);
    float s = ex;
#pragma unroll
    for (int off = 32; off > 0; off >>= 1) s += __shfl_xor(s, off, 64);
    out[(size_t)wid * 64 + lane] = v - m - logf(s);
}

extern "C" void kernel_launch(void* const* d_in, const int* in_sizes, int n_in,
                              void* d_out, int out_size, void* d_ws, size_t ws_size,
                              hipStream_t stream)
{
    const float* x     = (const float*)d_in[0];
    const int*   ei    = (const int*)  d_in[1];
    const float* ew    = (const float*)d_in[2];
    const float* W1    = (const float*)d_in[3];
    const float* b1    = (const float*)d_in[4];
    const float* gamma = (const float*)d_in[5];
    const float* beta  = (const float*)d_in[6];
    const float* W2    = (const float*)d_in[7];
    const float* b2    = (const float*)d_in[8];

    const int n = in_sizes[0] / 128;   // 100000
    const int e = in_sizes[2];         // 1600000
    const int* row = ei;               // edge_index[0]  (source)
    const int* col = ei + e;           // edge_index[1]  (target)

    // workspace layout (4-byte units):
    // dinv[n] | h1[n*128] (h2 aliases) | agg1[n*128] | bn[256] | scale[128] |
    // shift[128] | cnt[n] | ptr[n+1] | cur[n] | bsum[1024] | csr_src[e] | csr_nrm[e]
    float* ws    = (float*)d_ws;
    float* dinv  = ws;
    float* h1    = dinv + n;
    float* agg1  = h1 + (size_t)n * 128;
    float* bn    = agg1 + (size_t)n * 128;
    float* scale = bn + 256;
    float* shift = scale + 128;
    int*   cnt   = (int*)(shift + 128);
    int*   ptr   = cnt + n;
    int*   cur   = ptr + (n + 1);
    int*   bsum  = cur + n;
    int*   csr_src = bsum + 1024;
    float* csr_nrm = (float*)(csr_src + e);
    float* h2    = h1;                 // h1 dead after first gather
    float* outp  = (float*)d_out;

    const int nb_n = (n + 255) / 256;
    const int nb_e = (e + 255) / 256;
    const int nb_wpn = (n + 3) / 4;    // wave-per-node kernels: n*64 threads
    const int nblk_scan = (n + 1023) / 1024;

    // degrees + per-target edge counts
    k_init<<<nb_n, 256, 0, stream>>>(dinv, cnt, bn, n);
    k_deg_cnt<<<nb_e, 256, 0, stream>>>(col, ew, dinv, cnt, e);
    k_dinv<<<nb_n, 256, 0, stream>>>(dinv, n);

    // CSR build: scan cnt -> ptr/cur, then fill
    k_scanA<<<nblk_scan, 256, 0, stream>>>(cnt, bsum, n);
    k_scanB<<<1, 64, 0, stream>>>(bsum, ptr, nblk_scan, n);
    k_scanC<<<nblk_scan, 256, 0, stream>>>(cnt, bsum, ptr, cur, n);
    k_fill<<<nb_e, 256, 0, stream>>>(row, col, ew, dinv, cur, csr_src, csr_nrm, e);

    // ---- layer 1: h1 = x @ W1 ; agg1 = gather(h1) + b1 ----
    k_gemm<128, false><<<(n + 127) / 128, 256, 0, stream>>>(x, W1, nullptr, nullptr, h1, n);
    k_gather<128><<<nb_wpn, 256, 0, stream>>>(ptr, csr_src, csr_nrm, h1, dinv, b1, agg1, n);

    // ---- batchnorm stats -> scale/shift ----
    k_bn_stats<<<256, 256, 0, stream>>>(agg1, bn, bn + 128, n);
    k_bn_final<<<1, 128, 0, stream>>>(bn, gamma, beta, scale, shift, n);

    // ---- layer 2: h2 = relu(bn(agg1)) @ W2 ; out = gather(h2) + b2 ----
    k_gemm<64, true><<<(n + 127) / 128, 256, 0, stream>>>(agg1, W2, scale, shift, h2, n);
    k_gather<64><<<nb_wpn, 256, 0, stream>>>(ptr, csr_src, csr_nrm, h2, dinv, b2, outp, n);

    // ---- log_softmax in place ----
    k_lsm<<<nb_wpn, 256, 0, stream>>>(outp, n);
}

// Round 4
// 496.251 us; speedup vs baseline: 3.8586x; 1.2485x over previous
//
#include <hip/hip_runtime.h>
#include <math.h>

// ---------------------------------------------------------------------------
// TrafficGNN: 2-layer GCN + BN + ReLU + log_softmax.  All fp32.
// Round 4: CSR build with 1 atomic per edge (was 3).
//   k_cnt: rank[i] = atomicAdd(cnt[col[i]],1)   (counting + slot rank)
//   scan  -> ptr
//   k_fill: atomic-free scatter of (src, ew) int2 pairs
//   k_degsum: deg from CSR segments (no atomics) -> dinv
//   k_nrm: slot weight *= dinv[src]*dinv[tgt]
// ---------------------------------------------------------------------------

__device__ __forceinline__ void atomAddF(float* p, float v) {
    __hip_atomic_fetch_add(p, v, __ATOMIC_RELAXED, __HIP_MEMORY_SCOPE_AGENT);
}

// zero edge counters + zero BN accumulators
__global__ void k_init(int* __restrict__ cnt, float* __restrict__ bn, int n) {
    int i = blockIdx.x * 256 + threadIdx.x;
    if (i < n) cnt[i] = 0;
    if (i < 256) bn[i] = 0.0f;   // bn[0..127]=sum, bn[128..255]=sumsq
}

// rank[i] = slot index of edge i within its target's segment
__global__ void k_cnt(const int* __restrict__ col, int* __restrict__ cnt,
                      int* __restrict__ rank, int e) {
    int i = blockIdx.x * 256 + threadIdx.x;
    if (i < e) rank[i] = atomicAdd(&cnt[col[i]], 1);
}

// ---- exclusive scan of cnt[n] -> ptr[n+1] ----

__global__ __launch_bounds__(256)
void k_scanA(const int* __restrict__ cnt, int* __restrict__ bsum, int n) {
    __shared__ int ls[256];
    int base = blockIdx.x * 1024 + threadIdx.x * 4;
    int s = 0;
#pragma unroll
    for (int k = 0; k < 4; ++k) { int i = base + k; if (i < n) s += cnt[i]; }
    ls[threadIdx.x] = s;
    __syncthreads();
    for (int d = 128; d > 0; d >>= 1) {
        if (threadIdx.x < d) ls[threadIdx.x] += ls[threadIdx.x + d];
        __syncthreads();
    }
    if (threadIdx.x == 0) bsum[blockIdx.x] = ls[0];
}

__global__ void k_scanB(int* __restrict__ bsum, int* __restrict__ ptr,
                        int nblk, int n) {
    if (threadIdx.x == 0) {
        int run = 0;
        for (int i = 0; i < nblk; ++i) { int v = bsum[i]; bsum[i] = run; run += v; }
        ptr[n] = run;
    }
}

__global__ __launch_bounds__(256)
void k_scanC(const int* __restrict__ cnt, const int* __restrict__ bsum,
             int* __restrict__ ptr, int n) {
    __shared__ int ls[256];
    int base = blockIdx.x * 1024 + threadIdx.x * 4;
    int v[4];
#pragma unroll
    for (int k = 0; k < 4; ++k) { int i = base + k; v[k] = (i < n) ? cnt[i] : 0; }
    int t = v[0] + v[1] + v[2] + v[3];
    ls[threadIdx.x] = t;
    __syncthreads();
    for (int d = 1; d < 256; d <<= 1) {
        int mine = ls[threadIdx.x];
        int up   = (threadIdx.x >= d) ? ls[threadIdx.x - d] : 0;
        __syncthreads();
        ls[threadIdx.x] = mine + up;
        __syncthreads();
    }
    int off = bsum[blockIdx.x] + ls[threadIdx.x] - t;   // exclusive
    int pf = 0;
#pragma unroll
    for (int k = 0; k < 4; ++k) {
        int i = base + k;
        if (i < n) ptr[i] = off + pf;
        pf += v[k];
    }
}

// atomic-free CSR fill: slot = ptr[tgt] + rank; store (src, raw ew) pair
__global__ void k_fill(const int* __restrict__ row, const int* __restrict__ col,
                       const float* __restrict__ ew, const int* __restrict__ rank,
                       const int* __restrict__ ptr, int2* __restrict__ csr, int e) {
    int i = blockIdx.x * 256 + threadIdx.x;
    if (i < e) {
        int pos = ptr[col[i]] + rank[i];
        int2 pr;
        pr.x = row[i];
        pr.y = __float_as_int(ew[i]);
        csr[pos] = pr;
    }
}

// dinv[i] = rsqrt(1 + sum of ew over segment)    (16 lanes per node)
__global__ __launch_bounds__(256)
void k_degsum(const int* __restrict__ ptr, const int2* __restrict__ csr,
              float* __restrict__ dinv, int n) {
    int lane = threadIdx.x & 15;
    int node = (blockIdx.x * 256 + threadIdx.x) >> 4;
    if (node >= n) return;
    int p0 = ptr[node], p1 = ptr[node + 1];
    float s = 0.f;
    for (int j = p0 + lane; j < p1; j += 16) s += __int_as_float(csr[j].y);
#pragma unroll
    for (int off = 8; off > 0; off >>= 1) s += __shfl_xor(s, off, 16);
    if (lane == 0) dinv[node] = rsqrtf(1.0f + s);
}

// csr[j].w *= dinv[src]*dinv[tgt]    (16 lanes per node)
__global__ __launch_bounds__(256)
void k_nrm(const int* __restrict__ ptr, int2* __restrict__ csr,
           const float* __restrict__ dinv, int n) {
    int lane = threadIdx.x & 15;
    int node = (blockIdx.x * 256 + threadIdx.x) >> 4;
    if (node >= n) return;
    int p0 = ptr[node], p1 = ptr[node + 1];
    float di = dinv[node];
    for (int j = p0 + lane; j < p1; j += 16) {
        int2 pr = csr[j];
        pr.y = __float_as_int(__int_as_float(pr.y) * di * dinv[pr.x]);
        csr[j] = pr;
    }
}

// H[n,M] = X'[n,128] @ W[128,M], where X' = BN?relu(X*scale+shift):X
template<int M, bool BN>
__global__ __launch_bounds__(256)
void k_gemm(const float* __restrict__ X, const float* __restrict__ W,
            const float* __restrict__ scale, const float* __restrict__ shift,
            float* __restrict__ H, int n)
{
    constexpr int K = 128;
    constexpr int TK = 32;
    constexpr int CPT = M / 16;          // 8 (M=128) or 4 (M=64)
    __shared__ float xs[128][TK + 1];
    __shared__ float wsm[TK][M];

    const int t  = threadIdx.x;
    const int cg = t & 15;
    const int rg = t >> 4;
    const long long block_row = (long long)blockIdx.x * 128;

    float acc[8][CPT];
#pragma unroll
    for (int r = 0; r < 8; ++r)
#pragma unroll
        for (int c = 0; c < CPT; ++c) acc[r][c] = 0.f;

    const int xr0 = t >> 3;
    const int xc0 = (t & 7) * 4;

    for (int kp = 0; kp < K; kp += TK) {
#pragma unroll
        for (int i = 0; i < 4; ++i) {
            int r = xr0 + i * 32;
            long long gr = block_row + r;
            float4 v = make_float4(0.f, 0.f, 0.f, 0.f);
            if (gr < n) v = *(const float4*)(X + gr * K + kp + xc0);
            if (BN) {
                float4 sc = *(const float4*)(scale + kp + xc0);
                float4 sh = *(const float4*)(shift + kp + xc0);
                v.x = fmaxf(0.f, fmaf(v.x, sc.x, sh.x));
                v.y = fmaxf(0.f, fmaf(v.y, sc.y, sh.y));
                v.z = fmaxf(0.f, fmaf(v.z, sc.z, sh.z));
                v.w = fmaxf(0.f, fmaf(v.w, sc.w, sh.w));
            }
            xs[r][xc0 + 0] = v.x; xs[r][xc0 + 1] = v.y;
            xs[r][xc0 + 2] = v.z; xs[r][xc0 + 3] = v.w;
        }
        constexpr int WL = (TK * M) / (256 * 4);
#pragma unroll
        for (int j = 0; j < WL; ++j) {
            int idx = t + j * 256;
            int r  = idx / (M / 4);
            int c4 = (idx % (M / 4)) * 4;
            *(float4*)(&wsm[r][c4]) = *(const float4*)(W + (long long)(kp + r) * M + c4);
        }
        __syncthreads();
#pragma unroll
        for (int k = 0; k < TK; ++k) {
            float xv[8], wv[CPT];
#pragma unroll
            for (int r = 0; r < 8; ++r) xv[r] = xs[rg * 8 + r][k];
#pragma unroll
            for (int c = 0; c < CPT; ++c) wv[c] = wsm[k][cg * CPT + c];
#pragma unroll
            for (int r = 0; r < 8; ++r)
#pragma unroll
                for (int c = 0; c < CPT; ++c)
                    acc[r][c] = fmaf(xv[r], wv[c], acc[r][c]);
        }
        __syncthreads();
    }
#pragma unroll
    for (int r = 0; r < 8; ++r) {
        long long gr = block_row + rg * 8 + r;
        if (gr < n) {
#pragma unroll
            for (int c = 0; c < CPT; c += 4) {
                float4 v = make_float4(acc[r][c], acc[r][c + 1], acc[r][c + 2], acc[r][c + 3]);
                *(float4*)(H + gr * M + cg * CPT + c) = v;
            }
        }
    }
}

// CSR gather aggregation: one wave per node; lanes cover features.
// out[i] = bias + h[i]*dinv[i]^2 + sum_{j in in(i)} h[src[j]] * w[j]
template<int F>
__global__ __launch_bounds__(256)
void k_gather(const int* __restrict__ ptr, const int2* __restrict__ csr,
              const float* __restrict__ h, const float* __restrict__ dinv,
              const float* __restrict__ bias, float* __restrict__ out, int n)
{
    int lane = threadIdx.x & 63;
    int node = (blockIdx.x * 256 + threadIdx.x) >> 6;
    if (node >= n) return;
    int p0 = ptr[node], p1 = ptr[node + 1];
    float di = dinv[node];
    float s  = di * di;
    if (F == 128) {
        float2 hv = *(const float2*)(h + (size_t)node * 128 + lane * 2);
        float2 bv = *(const float2*)(bias + lane * 2);
        float2 acc = make_float2(fmaf(hv.x, s, bv.x), fmaf(hv.y, s, bv.y));
#pragma unroll 4
        for (int j = p0; j < p1; ++j) {
            int2 pr = csr[j];
            float w = __int_as_float(pr.y);
            float2 v = *(const float2*)(h + (size_t)pr.x * 128 + lane * 2);
            acc.x = fmaf(v.x, w, acc.x);
            acc.y = fmaf(v.y, w, acc.y);
        }
        *(float2*)(out + (size_t)node * 128 + lane * 2) = acc;
    } else {
        float acc = fmaf(h[(size_t)node * 64 + lane], s, bias[lane]);
#pragma unroll 4
        for (int j = p0; j < p1; ++j) {
            int2 pr = csr[j];
            float w = __int_as_float(pr.y);
            acc = fmaf(h[(size_t)pr.x * 64 + lane], w, acc);
        }
        out[(size_t)node * 64 + lane] = acc;
    }
}

// per-feature sum & sumsq over nodes (128 feats)
__global__ __launch_bounds__(256)
void k_bn_stats(const float* __restrict__ a, float* __restrict__ sums,
                float* __restrict__ sumsq, int n)
{
    int f = threadIdx.x & 127;
    int r0 = blockIdx.x * 2 + (threadIdx.x >> 7);
    float s = 0.f, q = 0.f;
    for (int r = r0; r < n; r += gridDim.x * 2) {
        float v = a[(size_t)r * 128 + f];
        s += v; q += v * v;
    }
    __shared__ float ls[256], lq[256];
    ls[threadIdx.x] = s; lq[threadIdx.x] = q;
    __syncthreads();
    if (threadIdx.x < 128) {
        atomAddF(&sums[f],  ls[threadIdx.x] + ls[threadIdx.x + 128]);
        atomAddF(&sumsq[f], lq[threadIdx.x] + lq[threadIdx.x + 128]);
    }
}

__global__ void k_bn_final(const float* __restrict__ bn, const float* __restrict__ gamma,
                           const float* __restrict__ beta, float* __restrict__ scale,
                           float* __restrict__ shift, int n)
{
    int f = threadIdx.x;
    if (f < 128) {
        float inv_n = 1.0f / (float)n;
        float mu  = bn[f] * inv_n;
        float var = bn[128 + f] * inv_n - mu * mu;
        float rstd = rsqrtf(var + 1e-5f);
        float sc = gamma[f] * rstd;
        scale[f] = sc;
        shift[f] = beta[f] - mu * sc;
    }
}

// in-place log_softmax over 64 features; one wave per node
__global__ __launch_bounds__(256)
void k_lsm(float* __restrict__ out, int n)
{
    int lane = threadIdx.x & 63;
    int wid  = (blockIdx.x * 256 + threadIdx.x) >> 6;
    if (wid >= n) return;
    float v = out[(size_t)wid * 64 + lane];
    float m = v;
#pragma unroll
    for (int off = 32; off > 0; off >>= 1) m = fmaxf(m, __shfl_xor(m, off, 64));
    float ex = expf(v - m);
    float s = ex;
#pragma unroll
    for (int off = 32; off > 0; off >>= 1) s += __shfl_xor(s, off, 64);
    out[(size_t)wid * 64 + lane] = v - m - logf(s);
}

extern "C" void kernel_launch(void* const* d_in, const int* in_sizes, int n_in,
                              void* d_out, int out_size, void* d_ws, size_t ws_size,
                              hipStream_t stream)
{
    const float* x     = (const float*)d_in[0];
    const int*   ei    = (const int*)  d_in[1];
    const float* ew    = (const float*)d_in[2];
    const float* W1    = (const float*)d_in[3];
    const float* b1    = (const float*)d_in[4];
    const float* gamma = (const float*)d_in[5];
    const float* beta  = (const float*)d_in[6];
    const float* W2    = (const float*)d_in[7];
    const float* b2    = (const float*)d_in[8];

    const int n = in_sizes[0] / 128;   // 100000
    const int e = in_sizes[2];         // 1600000
    const int* row = ei;               // edge_index[0]  (source)
    const int* col = ei + e;           // edge_index[1]  (target)

    // workspace layout (4-byte units):
    // dinv[n] | h1[n*128] (h2 aliases) | agg1[n*128] (rank aliases) | bn[256] |
    // scale[128] | shift[128] | cnt[n] | ptr[n+1] | bsum[1024] | csr[e] (int2)
    float* ws    = (float*)d_ws;
    size_t off   = 0;
    float* dinv  = ws + off; off += n;
    float* h1    = ws + off; off += (size_t)n * 128;
    float* agg1  = ws + off; off += (size_t)n * 128;
    float* bn    = ws + off; off += 256;
    float* scale = ws + off; off += 128;
    float* shift = ws + off; off += 128;
    int*   cnt   = (int*)(ws + off); off += n;
    int*   ptr   = (int*)(ws + off); off += (size_t)(n + 1);
    int*   bsum  = (int*)(ws + off); off += 1024;
    off = (off + 1) & ~(size_t)1;       // 8-byte align for int2
    int2*  csr   = (int2*)(ws + off);
    int*   rank  = (int*)agg1;          // agg1 dead until k_gather<128>
    float* h2    = h1;                  // h1 dead after first gather
    float* outp  = (float*)d_out;

    const int nb_n = (n + 255) / 256;
    const int nb_e = (e + 255) / 256;
    const int nb_wpn = (n + 3) / 4;     // wave-per-node: n*64 threads
    const int nb_qpn = (n + 15) / 16;   // 16-lane-group-per-node: n*16 threads
    const int nblk_scan = (n + 1023) / 1024;

    // CSR build: count(+rank) -> scan -> fill -> degsum -> nrm
    k_init<<<nb_n, 256, 0, stream>>>(cnt, bn, n);
    k_cnt<<<nb_e, 256, 0, stream>>>(col, cnt, rank, e);
    k_scanA<<<nblk_scan, 256, 0, stream>>>(cnt, bsum, n);
    k_scanB<<<1, 64, 0, stream>>>(bsum, ptr, nblk_scan, n);
    k_scanC<<<nblk_scan, 256, 0, stream>>>(cnt, bsum, ptr, n);
    k_fill<<<nb_e, 256, 0, stream>>>(row, col, ew, rank, ptr, csr, e);
    k_degsum<<<nb_qpn, 256, 0, stream>>>(ptr, csr, dinv, n);
    k_nrm<<<nb_qpn, 256, 0, stream>>>(ptr, csr, dinv, n);

    // ---- layer 1: h1 = x @ W1 ; agg1 = gather(h1) + b1 ----
    k_gemm<128, false><<<(n + 127) / 128, 256, 0, stream>>>(x, W1, nullptr, nullptr, h1, n);
    k_gather<128><<<nb_wpn, 256, 0, stream>>>(ptr, csr, h1, dinv, b1, agg1, n);

    // ---- batchnorm stats -> scale/shift ----
    k_bn_stats<<<256, 256, 0, stream>>>(agg1, bn, bn + 128, n);
    k_bn_final<<<1, 128, 0, stream>>>(bn, gamma, beta, scale, shift, n);

    // ---- layer 2: h2 = relu(bn(agg1)) @ W2 ; out = gather(h2) + b2 ----
    k_gemm<64, true><<<(n + 127) / 128, 256, 0, stream>>>(agg1, W2, scale, shift, h2, n);
    k_gather<64><<<nb_wpn, 256, 0, stream>>>(ptr, csr, h2, dinv, b2, outp, n);

    // ---- log_softmax in place ----
    k_lsm<<<nb_wpn, 256, 0, stream>>>(outp, n);
}

// Round 5
// 432.756 us; speedup vs baseline: 4.4248x; 1.1467x over previous
//
#include <hip/hip_runtime.h>
#include <math.h>

// ---------------------------------------------------------------------------
// TrafficGNN: 2-layer GCN + BN + ReLU + log_softmax.
// Round 5: h1/h2 stored as bf16 (fp32 accum) -> gather traffic halved;
//          log_softmax fused into k_gather<64> epilogue.
// ---------------------------------------------------------------------------

typedef unsigned int  uint;
typedef unsigned short ushort;

__device__ __forceinline__ void atomAddF(float* p, float v) {
    __hip_atomic_fetch_add(p, v, __ATOMIC_RELAXED, __HIP_MEMORY_SCOPE_AGENT);
}

// float -> bf16 (round to nearest even)
__device__ __forceinline__ ushort f2bf(float f) {
    uint u = __float_as_uint(f);
    u += 0x7FFFu + ((u >> 16) & 1u);
    return (ushort)(u >> 16);
}
__device__ __forceinline__ float bf2f(ushort h) {
    return __uint_as_float(((uint)h) << 16);
}
// pack two floats -> uint (f0 in low 16, f1 in high 16)
__device__ __forceinline__ uint pack2(float f0, float f1) {
    return (uint)f2bf(f0) | ((uint)f2bf(f1) << 16);
}

// zero edge counters + zero BN accumulators
__global__ void k_init(int* __restrict__ cnt, float* __restrict__ bn, int n) {
    int i = blockIdx.x * 256 + threadIdx.x;
    if (i < n) cnt[i] = 0;
    if (i < 256) bn[i] = 0.0f;   // bn[0..127]=sum, bn[128..255]=sumsq
}

// rank[i] = slot index of edge i within its target's segment
__global__ void k_cnt(const int* __restrict__ col, int* __restrict__ cnt,
                      int* __restrict__ rank, int e) {
    int i = blockIdx.x * 256 + threadIdx.x;
    if (i < e) rank[i] = atomicAdd(&cnt[col[i]], 1);
}

// ---- exclusive scan of cnt[n] -> ptr[n+1] ----

__global__ __launch_bounds__(256)
void k_scanA(const int* __restrict__ cnt, int* __restrict__ bsum, int n) {
    __shared__ int ls[256];
    int base = blockIdx.x * 1024 + threadIdx.x * 4;
    int s = 0;
#pragma unroll
    for (int k = 0; k < 4; ++k) { int i = base + k; if (i < n) s += cnt[i]; }
    ls[threadIdx.x] = s;
    __syncthreads();
    for (int d = 128; d > 0; d >>= 1) {
        if (threadIdx.x < d) ls[threadIdx.x] += ls[threadIdx.x + d];
        __syncthreads();
    }
    if (threadIdx.x == 0) bsum[blockIdx.x] = ls[0];
}

__global__ void k_scanB(int* __restrict__ bsum, int* __restrict__ ptr,
                        int nblk, int n) {
    if (threadIdx.x == 0) {
        int run = 0;
        for (int i = 0; i < nblk; ++i) { int v = bsum[i]; bsum[i] = run; run += v; }
        ptr[n] = run;
    }
}

__global__ __launch_bounds__(256)
void k_scanC(const int* __restrict__ cnt, const int* __restrict__ bsum,
             int* __restrict__ ptr, int n) {
    __shared__ int ls[256];
    int base = blockIdx.x * 1024 + threadIdx.x * 4;
    int v[4];
#pragma unroll
    for (int k = 0; k < 4; ++k) { int i = base + k; v[k] = (i < n) ? cnt[i] : 0; }
    int t = v[0] + v[1] + v[2] + v[3];
    ls[threadIdx.x] = t;
    __syncthreads();
    for (int d = 1; d < 256; d <<= 1) {
        int mine = ls[threadIdx.x];
        int up   = (threadIdx.x >= d) ? ls[threadIdx.x - d] : 0;
        __syncthreads();
        ls[threadIdx.x] = mine + up;
        __syncthreads();
    }
    int off = bsum[blockIdx.x] + ls[threadIdx.x] - t;   // exclusive
    int pf = 0;
#pragma unroll
    for (int k = 0; k < 4; ++k) {
        int i = base + k;
        if (i < n) ptr[i] = off + pf;
        pf += v[k];
    }
}

// atomic-free CSR fill: slot = ptr[tgt] + rank; store (src, raw ew) pair
__global__ void k_fill(const int* __restrict__ row, const int* __restrict__ col,
                       const float* __restrict__ ew, const int* __restrict__ rank,
                       const int* __restrict__ ptr, int2* __restrict__ csr, int e) {
    int i = blockIdx.x * 256 + threadIdx.x;
    if (i < e) {
        int pos = ptr[col[i]] + rank[i];
        int2 pr;
        pr.x = row[i];
        pr.y = __float_as_int(ew[i]);
        csr[pos] = pr;
    }
}

// dinv[i] = rsqrt(1 + sum of ew over segment)    (16 lanes per node)
__global__ __launch_bounds__(256)
void k_degsum(const int* __restrict__ ptr, const int2* __restrict__ csr,
              float* __restrict__ dinv, int n) {
    int lane = threadIdx.x & 15;
    int node = (blockIdx.x * 256 + threadIdx.x) >> 4;
    if (node >= n) return;
    int p0 = ptr[node], p1 = ptr[node + 1];
    float s = 0.f;
    for (int j = p0 + lane; j < p1; j += 16) s += __int_as_float(csr[j].y);
#pragma unroll
    for (int off = 8; off > 0; off >>= 1) s += __shfl_xor(s, off, 16);
    if (lane == 0) dinv[node] = rsqrtf(1.0f + s);
}

// csr[j].w *= dinv[src]*dinv[tgt]    (16 lanes per node)
__global__ __launch_bounds__(256)
void k_nrm(const int* __restrict__ ptr, int2* __restrict__ csr,
           const float* __restrict__ dinv, int n) {
    int lane = threadIdx.x & 15;
    int node = (blockIdx.x * 256 + threadIdx.x) >> 4;
    if (node >= n) return;
    int p0 = ptr[node], p1 = ptr[node + 1];
    float di = dinv[node];
    for (int j = p0 + lane; j < p1; j += 16) {
        int2 pr = csr[j];
        pr.y = __float_as_int(__int_as_float(pr.y) * di * dinv[pr.x]);
        csr[j] = pr;
    }
}

// H[n,M](bf16) = X'[n,128](f32) @ W[128,M], X' = BN?relu(X*scale+shift):X
template<int M, bool BN>
__global__ __launch_bounds__(256)
void k_gemm(const float* __restrict__ X, const float* __restrict__ W,
            const float* __restrict__ scale, const float* __restrict__ shift,
            ushort* __restrict__ H, int n)
{
    constexpr int K = 128;
    constexpr int TK = 32;
    constexpr int CPT = M / 16;          // 8 (M=128) or 4 (M=64)
    __shared__ float xs[128][TK + 1];
    __shared__ float wsm[TK][M];

    const int t  = threadIdx.x;
    const int cg = t & 15;
    const int rg = t >> 4;
    const long long block_row = (long long)blockIdx.x * 128;

    float acc[8][CPT];
#pragma unroll
    for (int r = 0; r < 8; ++r)
#pragma unroll
        for (int c = 0; c < CPT; ++c) acc[r][c] = 0.f;

    const int xr0 = t >> 3;
    const int xc0 = (t & 7) * 4;

    for (int kp = 0; kp < K; kp += TK) {
#pragma unroll
        for (int i = 0; i < 4; ++i) {
            int r = xr0 + i * 32;
            long long gr = block_row + r;
            float4 v = make_float4(0.f, 0.f, 0.f, 0.f);
            if (gr < n) v = *(const float4*)(X + gr * K + kp + xc0);
            if (BN) {
                float4 sc = *(const float4*)(scale + kp + xc0);
                float4 sh = *(const float4*)(shift + kp + xc0);
                v.x = fmaxf(0.f, fmaf(v.x, sc.x, sh.x));
                v.y = fmaxf(0.f, fmaf(v.y, sc.y, sh.y));
                v.z = fmaxf(0.f, fmaf(v.z, sc.z, sh.z));
                v.w = fmaxf(0.f, fmaf(v.w, sc.w, sh.w));
            }
            xs[r][xc0 + 0] = v.x; xs[r][xc0 + 1] = v.y;
            xs[r][xc0 + 2] = v.z; xs[r][xc0 + 3] = v.w;
        }
        constexpr int WL = (TK * M) / (256 * 4);
#pragma unroll
        for (int j = 0; j < WL; ++j) {
            int idx = t + j * 256;
            int r  = idx / (M / 4);
            int c4 = (idx % (M / 4)) * 4;
            *(float4*)(&wsm[r][c4]) = *(const float4*)(W + (long long)(kp + r) * M + c4);
        }
        __syncthreads();
#pragma unroll
        for (int k = 0; k < TK; ++k) {
            float xv[8], wv[CPT];
#pragma unroll
            for (int r = 0; r < 8; ++r) xv[r] = xs[rg * 8 + r][k];
#pragma unroll
            for (int c = 0; c < CPT; ++c) wv[c] = wsm[k][cg * CPT + c];
#pragma unroll
            for (int r = 0; r < 8; ++r)
#pragma unroll
                for (int c = 0; c < CPT; ++c)
                    acc[r][c] = fmaf(xv[r], wv[c], acc[r][c]);
        }
        __syncthreads();
    }
#pragma unroll
    for (int r = 0; r < 8; ++r) {
        long long gr = block_row + rg * 8 + r;
        if (gr < n) {
            if (M == 128) {
                uint4 o;
                o.x = pack2(acc[r][0], acc[r][1]);
                o.y = pack2(acc[r][2], acc[r][3]);
                o.z = pack2(acc[r][4], acc[r][5]);
                o.w = pack2(acc[r][6], acc[r][7]);
                *(uint4*)(H + gr * M + cg * CPT) = o;
            } else {
                uint2 o;
                o.x = pack2(acc[r][0], acc[r][1]);
                o.y = pack2(acc[r][2], acc[r][3]);
                *(uint2*)(H + gr * M + cg * CPT) = o;
            }
        }
    }
}

// layer-1 gather: out(f32) = b1 + h[i]*dinv^2 + sum h[src]*w ; h is bf16[n][128]
__global__ __launch_bounds__(256)
void k_gather1(const int* __restrict__ ptr, const int2* __restrict__ csr,
               const ushort* __restrict__ h, const float* __restrict__ dinv,
               const float* __restrict__ bias, float* __restrict__ out, int n)
{
    int lane = threadIdx.x & 63;
    int node = (blockIdx.x * 256 + threadIdx.x) >> 6;
    if (node >= n) return;
    int p0 = ptr[node], p1 = ptr[node + 1];
    float di = dinv[node];
    float s  = di * di;
    uint hv = *(const uint*)(h + (size_t)node * 128 + lane * 2);
    float2 bv = *(const float2*)(bias + lane * 2);
    float accx = fmaf(bf2f((ushort)hv), s, bv.x);
    float accy = fmaf(bf2f((ushort)(hv >> 16)), s, bv.y);
#pragma unroll 4
    for (int j = p0; j < p1; ++j) {
        int2 pr = csr[j];
        float w = __int_as_float(pr.y);
        uint v = *(const uint*)(h + (size_t)pr.x * 128 + lane * 2);
        accx = fmaf(bf2f((ushort)v), w, accx);
        accy = fmaf(bf2f((ushort)(v >> 16)), w, accy);
    }
    *(float2*)(out + (size_t)node * 128 + lane * 2) = make_float2(accx, accy);
}

// layer-2 gather + fused log_softmax: h is bf16[n][64]; writes final output
__global__ __launch_bounds__(256)
void k_gather2(const int* __restrict__ ptr, const int2* __restrict__ csr,
               const ushort* __restrict__ h, const float* __restrict__ dinv,
               const float* __restrict__ bias, float* __restrict__ out, int n)
{
    int lane = threadIdx.x & 63;
    int node = (blockIdx.x * 256 + threadIdx.x) >> 6;
    if (node >= n) return;
    int p0 = ptr[node], p1 = ptr[node + 1];
    float di = dinv[node];
    float s  = di * di;
    float acc = fmaf(bf2f(h[(size_t)node * 64 + lane]), s, bias[lane]);
#pragma unroll 4
    for (int j = p0; j < p1; ++j) {
        int2 pr = csr[j];
        float w = __int_as_float(pr.y);
        acc = fmaf(bf2f(h[(size_t)pr.x * 64 + lane]), w, acc);
    }
    // fused log_softmax across the wave's 64 lanes
    float m = acc;
#pragma unroll
    for (int off = 32; off > 0; off >>= 1) m = fmaxf(m, __shfl_xor(m, off, 64));
    float ex = expf(acc - m);
    float sum = ex;
#pragma unroll
    for (int off = 32; off > 0; off >>= 1) sum += __shfl_xor(sum, off, 64);
    out[(size_t)node * 64 + lane] = acc - m - logf(sum);
}

// per-feature sum & sumsq over nodes (128 feats)
__global__ __launch_bounds__(256)
void k_bn_stats(const float* __restrict__ a, float* __restrict__ sums,
                float* __restrict__ sumsq, int n)
{
    int f = threadIdx.x & 127;
    int r0 = blockIdx.x * 2 + (threadIdx.x >> 7);
    float s = 0.f, q = 0.f;
    for (int r = r0; r < n; r += gridDim.x * 2) {
        float v = a[(size_t)r * 128 + f];
        s += v; q += v * v;
    }
    __shared__ float ls[256], lq[256];
    ls[threadIdx.x] = s; lq[threadIdx.x] = q;
    __syncthreads();
    if (threadIdx.x < 128) {
        atomAddF(&sums[f],  ls[threadIdx.x] + ls[threadIdx.x + 128]);
        atomAddF(&sumsq[f], lq[threadIdx.x] + lq[threadIdx.x + 128]);
    }
}

__global__ void k_bn_final(const float* __restrict__ bn, const float* __restrict__ gamma,
                           const float* __restrict__ beta, float* __restrict__ scale,
                           float* __restrict__ shift, int n)
{
    int f = threadIdx.x;
    if (f < 128) {
        float inv_n = 1.0f / (float)n;
        float mu  = bn[f] * inv_n;
        float var = bn[128 + f] * inv_n - mu * mu;
        float rstd = rsqrtf(var + 1e-5f);
        float sc = gamma[f] * rstd;
        scale[f] = sc;
        shift[f] = beta[f] - mu * sc;
    }
}

extern "C" void kernel_launch(void* const* d_in, const int* in_sizes, int n_in,
                              void* d_out, int out_size, void* d_ws, size_t ws_size,
                              hipStream_t stream)
{
    const float* x     = (const float*)d_in[0];
    const int*   ei    = (const int*)  d_in[1];
    const float* ew    = (const float*)d_in[2];
    const float* W1    = (const float*)d_in[3];
    const float* b1    = (const float*)d_in[4];
    const float* gamma = (const float*)d_in[5];
    const float* beta  = (const float*)d_in[6];
    const float* W2    = (const float*)d_in[7];
    const float* b2    = (const float*)d_in[8];

    const int n = in_sizes[0] / 128;   // 100000
    const int e = in_sizes[2];         // 1600000
    const int* row = ei;               // edge_index[0]  (source)
    const int* col = ei + e;           // edge_index[1]  (target)

    // workspace layout (4-byte units):
    // dinv[n] | h1 bf16[n*128] (h2 bf16[n*64] aliases) | agg1 f32[n*128]
    // (rank aliases) | bn[256] | scale[128] | shift[128] | cnt[n] | ptr[n+1] |
    // bsum[1024] | csr[e] (int2)
    float* ws    = (float*)d_ws;
    size_t off   = 0;
    float* dinv  = ws + off; off += n;
    ushort* h1   = (ushort*)(ws + off); off += (size_t)n * 64;  // n*128 bf16
    float* agg1  = ws + off; off += (size_t)n * 128;
    float* bn    = ws + off; off += 256;
    float* scale = ws + off; off += 128;
    float* shift = ws + off; off += 128;
    int*   cnt   = (int*)(ws + off); off += n;
    int*   ptr   = (int*)(ws + off); off += (size_t)(n + 1);
    int*   bsum  = (int*)(ws + off); off += 1024;
    off = (off + 1) & ~(size_t)1;       // 8-byte align for int2
    int2*  csr   = (int2*)(ws + off);
    int*   rank  = (int*)agg1;          // agg1 dead until k_gather1
    ushort* h2   = h1;                  // h1 dead after k_gather1
    float* outp  = (float*)d_out;

    const int nb_n = (n + 255) / 256;
    const int nb_e = (e + 255) / 256;
    const int nb_wpn = (n + 3) / 4;     // wave-per-node: n*64 threads
    const int nb_qpn = (n + 15) / 16;   // 16-lane-group-per-node
    const int nblk_scan = (n + 1023) / 1024;

    // CSR build: count(+rank) -> scan -> fill -> degsum -> nrm
    k_init<<<nb_n, 256, 0, stream>>>(cnt, bn, n);
    k_cnt<<<nb_e, 256, 0, stream>>>(col, cnt, rank, e);
    k_scanA<<<nblk_scan, 256, 0, stream>>>(cnt, bsum, n);
    k_scanB<<<1, 64, 0, stream>>>(bsum, ptr, nblk_scan, n);
    k_scanC<<<nblk_scan, 256, 0, stream>>>(cnt, bsum, ptr, n);
    k_fill<<<nb_e, 256, 0, stream>>>(row, col, ew, rank, ptr, csr, e);
    k_degsum<<<nb_qpn, 256, 0, stream>>>(ptr, csr, dinv, n);
    k_nrm<<<nb_qpn, 256, 0, stream>>>(ptr, csr, dinv, n);

    // ---- layer 1: h1 = x @ W1 (bf16) ; agg1 = gather(h1) + b1 (f32) ----
    k_gemm<128, false><<<(n + 127) / 128, 256, 0, stream>>>(x, W1, nullptr, nullptr, h1, n);
    k_gather1<<<nb_wpn, 256, 0, stream>>>(ptr, csr, h1, dinv, b1, agg1, n);

    // ---- batchnorm stats -> scale/shift ----
    k_bn_stats<<<256, 256, 0, stream>>>(agg1, bn, bn + 128, n);
    k_bn_final<<<1, 128, 0, stream>>>(bn, gamma, beta, scale, shift, n);

    // ---- layer 2: h2 = relu(bn(agg1)) @ W2 (bf16) ; out = gather(h2)+b2, lsm ----
    k_gemm<64, true><<<(n + 127) / 128, 256, 0, stream>>>(agg1, W2, scale, shift, h2, n);
    k_gather2<<<nb_wpn, 256, 0, stream>>>(ptr, csr, h2, dinv, b2, outp, n);
}

// Round 7
// 371.838 us; speedup vs baseline: 5.1497x; 1.1638x over previous
//
#include <hip/hip_runtime.h>
#include <math.h>

// ---------------------------------------------------------------------------
// TrafficGNN: 2-layer GCN + BN + ReLU + log_softmax.
// Round 7: fix Round-6 workspace overflow (w1f/w2f were reserved at half
// size in float units; W1-frags clobbered w2f, W2-frags spilled into csr
// whose edge records then fed NaN bf16 patterns into layer-2 MFMA).
// ---------------------------------------------------------------------------

typedef unsigned int   uint;
typedef unsigned short ushort;
typedef __bf16 bf16x8 __attribute__((ext_vector_type(8)));
typedef float  f32x4  __attribute__((ext_vector_type(4)));

union U16 { uint4 u; bf16x8 b; };

__device__ __forceinline__ void atomAddF(float* p, float v) {
    __hip_atomic_fetch_add(p, v, __ATOMIC_RELAXED, __HIP_MEMORY_SCOPE_AGENT);
}

// float -> bf16 (round to nearest even)
__device__ __forceinline__ ushort f2bf(float f) {
    uint u = __float_as_uint(f);
    u += 0x7FFFu + ((u >> 16) & 1u);
    return (ushort)(u >> 16);
}
__device__ __forceinline__ float bf2f(ushort h) {
    return __uint_as_float(((uint)h) << 16);
}
__device__ __forceinline__ uint pack2(float f0, float f1) {
    return (uint)f2bf(f0) | ((uint)f2bf(f1) << 16);
}

// zero edge counters + zero BN accumulators
__global__ void k_init(int* __restrict__ cnt, float* __restrict__ bn, int n) {
    int i = blockIdx.x * 256 + threadIdx.x;
    if (i < n) cnt[i] = 0;
    if (i < 256) bn[i] = 0.0f;   // bn[0..127]=sum, bn[128..255]=sumsq
}

// rank[i] = slot index of edge i within its target's segment
__global__ void k_cnt(const int* __restrict__ col, int* __restrict__ cnt,
                      int* __restrict__ rank, int e) {
    int i = blockIdx.x * 256 + threadIdx.x;
    if (i < e) rank[i] = atomicAdd(&cnt[col[i]], 1);
}

// ---- exclusive scan of cnt[n] -> ptr[n+1] ----

__global__ __launch_bounds__(256)
void k_scanA(const int* __restrict__ cnt, int* __restrict__ bsum, int n) {
    __shared__ int ls[256];
    int base = blockIdx.x * 1024 + threadIdx.x * 4;
    int s = 0;
#pragma unroll
    for (int k = 0; k < 4; ++k) { int i = base + k; if (i < n) s += cnt[i]; }
    ls[threadIdx.x] = s;
    __syncthreads();
    for (int d = 128; d > 0; d >>= 1) {
        if (threadIdx.x < d) ls[threadIdx.x] += ls[threadIdx.x + d];
        __syncthreads();
    }
    if (threadIdx.x == 0) bsum[blockIdx.x] = ls[0];
}

__global__ void k_scanB(int* __restrict__ bsum, int* __restrict__ ptr,
                        int nblk, int n) {
    if (threadIdx.x == 0) {
        int run = 0;
        for (int i = 0; i < nblk; ++i) { int v = bsum[i]; bsum[i] = run; run += v; }
        ptr[n] = run;
    }
}

__global__ __launch_bounds__(256)
void k_scanC(const int* __restrict__ cnt, const int* __restrict__ bsum,
             int* __restrict__ ptr, int n) {
    __shared__ int ls[256];
    int base = blockIdx.x * 1024 + threadIdx.x * 4;
    int v[4];
#pragma unroll
    for (int k = 0; k < 4; ++k) { int i = base + k; v[k] = (i < n) ? cnt[i] : 0; }
    int t = v[0] + v[1] + v[2] + v[3];
    ls[threadIdx.x] = t;
    __syncthreads();
    for (int d = 1; d < 256; d <<= 1) {
        int mine = ls[threadIdx.x];
        int up   = (threadIdx.x >= d) ? ls[threadIdx.x - d] : 0;
        __syncthreads();
        ls[threadIdx.x] = mine + up;
        __syncthreads();
    }
    int off = bsum[blockIdx.x] + ls[threadIdx.x] - t;   // exclusive
    int pf = 0;
#pragma unroll
    for (int k = 0; k < 4; ++k) {
        int i = base + k;
        if (i < n) ptr[i] = off + pf;
        pf += v[k];
    }
}

// atomic-free CSR fill: slot = ptr[tgt] + rank; store (src, raw ew) pair
__global__ void k_fill(const int* __restrict__ row, const int* __restrict__ col,
                       const float* __restrict__ ew, const int* __restrict__ rank,
                       const int* __restrict__ ptr, int2* __restrict__ csr, int e) {
    int i = blockIdx.x * 256 + threadIdx.x;
    if (i < e) {
        int pos = ptr[col[i]] + rank[i];
        int2 pr;
        pr.x = row[i];
        pr.y = __float_as_int(ew[i]);
        csr[pos] = pr;
    }
}

// dinv[i] = rsqrt(1 + sum of ew over segment)    (16 lanes per node)
__global__ __launch_bounds__(256)
void k_degsum(const int* __restrict__ ptr, const int2* __restrict__ csr,
              float* __restrict__ dinv, int n) {
    int lane = threadIdx.x & 15;
    int node = (blockIdx.x * 256 + threadIdx.x) >> 4;
    if (node >= n) return;
    int p0 = ptr[node], p1 = ptr[node + 1];
    float s = 0.f;
    for (int j = p0 + lane; j < p1; j += 16) s += __int_as_float(csr[j].y);
#pragma unroll
    for (int off = 8; off > 0; off >>= 1) s += __shfl_xor(s, off, 16);
    if (lane == 0) dinv[node] = rsqrtf(1.0f + s);
}

// csr[j].w *= dinv[src]*dinv[tgt]    (16 lanes per node)
__global__ __launch_bounds__(256)
void k_nrm(const int* __restrict__ ptr, int2* __restrict__ csr,
           const float* __restrict__ dinv, int n) {
    int lane = threadIdx.x & 15;
    int node = (blockIdx.x * 256 + threadIdx.x) >> 4;
    if (node >= n) return;
    int p0 = ptr[node], p1 = ptr[node + 1];
    float di = dinv[node];
    for (int j = p0 + lane; j < p1; j += 16) {
        int2 pr = csr[j];
        pr.y = __float_as_int(__int_as_float(pr.y) * di * dinv[pr.x]);
        csr[j] = pr;
    }
}

// W[128][M] f32 row-major -> bf16 fragment order: frag[(nt*4+ks)*64+l][j] =
// W[ks*32 + (l>>4)*8 + j][nt*16 + (l&15)].  One thread per fragment (t = idx).
__global__ void k_wfrag(const float* __restrict__ W, uint4* __restrict__ Wf, int M) {
    int t = blockIdx.x * 256 + threadIdx.x;
    if (t >= M * 16) return;            // M/16 nt * 4 ks * 64 lanes
    int l  = t & 63;
    int ks = (t >> 6) & 3;
    int nt = t >> 8;
    int kbase = ks * 32 + (l >> 4) * 8;
    int colj  = nt * 16 + (l & 15);
    float v[8];
#pragma unroll
    for (int j = 0; j < 8; ++j) v[j] = W[(kbase + j) * M + colj];
    uint4 o;
    o.x = pack2(v[0], v[1]);
    o.y = pack2(v[2], v[3]);
    o.z = pack2(v[4], v[5]);
    o.w = pack2(v[6], v[7]);
    Wf[t] = o;
}

// H[n,M](bf16) = X'[n,128](f32) @ W[128,M] via 16x16x32 bf16 MFMA.
// X' = BN ? relu(X*scale+shift) : X.  4 waves/block, wave = 16 rows x M cols.
template<int M, bool BN>
__global__ __launch_bounds__(256)
void k_mfma(const float* __restrict__ X, const uint4* __restrict__ Wf,
            const float* __restrict__ scale, const float* __restrict__ shift,
            ushort* __restrict__ H, int n)
{
    constexpr int NT = M / 16;           // N-tiles per wave
    const int l = threadIdx.x & 63;
    const int w = threadIdx.x >> 6;
    const int rowbase = blockIdx.x * 64 + w * 16;
    const int arow = rowbase + (l & 15);
    const bool rv = arow < n;
    const int koff = (l >> 4) * 8;       // this lane's k-chunk within a K-step

    f32x4 acc[NT];
#pragma unroll
    for (int t = 0; t < NT; ++t) acc[t] = (f32x4){0.f, 0.f, 0.f, 0.f};

    const float* xr = X + (size_t)arow * 128 + koff;

#pragma unroll
    for (int ks = 0; ks < 4; ++ks) {
        float4 a0 = make_float4(0.f, 0.f, 0.f, 0.f);
        float4 a1 = a0;
        if (rv) {
            a0 = *(const float4*)(xr + ks * 32);
            a1 = *(const float4*)(xr + ks * 32 + 4);
        }
        if (BN) {
            int k0 = ks * 32 + koff;
            float4 sc0 = *(const float4*)(scale + k0);
            float4 sc1 = *(const float4*)(scale + k0 + 4);
            float4 sh0 = *(const float4*)(shift + k0);
            float4 sh1 = *(const float4*)(shift + k0 + 4);
            a0.x = fmaxf(0.f, fmaf(a0.x, sc0.x, sh0.x));
            a0.y = fmaxf(0.f, fmaf(a0.y, sc0.y, sh0.y));
            a0.z = fmaxf(0.f, fmaf(a0.z, sc0.z, sh0.z));
            a0.w = fmaxf(0.f, fmaf(a0.w, sc0.w, sh0.w));
            a1.x = fmaxf(0.f, fmaf(a1.x, sc1.x, sh1.x));
            a1.y = fmaxf(0.f, fmaf(a1.y, sc1.y, sh1.y));
            a1.z = fmaxf(0.f, fmaf(a1.z, sc1.z, sh1.z));
            a1.w = fmaxf(0.f, fmaf(a1.w, sc1.w, sh1.w));
        }
        U16 ua;
        ua.u.x = pack2(a0.x, a0.y);
        ua.u.y = pack2(a0.z, a0.w);
        ua.u.z = pack2(a1.x, a1.y);
        ua.u.w = pack2(a1.z, a1.w);
#pragma unroll
        for (int nt = 0; nt < NT; ++nt) {
            U16 ub;
            ub.u = Wf[(nt * 4 + ks) * 64 + l];
            acc[nt] = __builtin_amdgcn_mfma_f32_16x16x32_bf16(ua.b, ub.b, acc[nt], 0, 0, 0);
        }
    }

    // epilogue: transpose through padded LDS, then coalesced 16B stores.
    // C/D layout: col = l&15, row = (l>>4)*4 + reg   [m89]
    __shared__ __align__(16) ushort lds[4][16][M + 8];
#pragma unroll
    for (int nt = 0; nt < NT; ++nt)
#pragma unroll
        for (int r = 0; r < 4; ++r)
            lds[w][(l >> 4) * 4 + r][nt * 16 + (l & 15)] = f2bf(acc[nt][r]);
    __syncthreads();

    constexpr int LPR = M / 8;           // lanes per output row (16B each)
    constexpr int RPP = 64 / LPR;        // rows per pass
#pragma unroll
    for (int it = 0; it < 16 / RPP; ++it) {
        int rl = it * RPP + (l / LPR);
        int gr = rowbase + rl;
        if (gr < n)
            *(uint4*)(H + (size_t)gr * M + (l % LPR) * 8) =
                *(const uint4*)&lds[w][rl][(l % LPR) * 8];
    }
}

// layer-1 gather: out(f32) = b1 + h[i]*dinv^2 + sum h[src]*w ; h is bf16[n][128]
__global__ __launch_bounds__(256)
void k_gather1(const int* __restrict__ ptr, const int2* __restrict__ csr,
               const ushort* __restrict__ h, const float* __restrict__ dinv,
               const float* __restrict__ bias, float* __restrict__ out, int n)
{
    int lane = threadIdx.x & 63;
    int node = (blockIdx.x * 256 + threadIdx.x) >> 6;
    if (node >= n) return;
    int p0 = ptr[node], p1 = ptr[node + 1];
    float di = dinv[node];
    float s  = di * di;
    uint hv = *(const uint*)(h + (size_t)node * 128 + lane * 2);
    float2 bv = *(const float2*)(bias + lane * 2);
    float accx = fmaf(bf2f((ushort)hv), s, bv.x);
    float accy = fmaf(bf2f((ushort)(hv >> 16)), s, bv.y);
#pragma unroll 4
    for (int j = p0; j < p1; ++j) {
        int2 pr = csr[j];
        float w = __int_as_float(pr.y);
        uint v = *(const uint*)(h + (size_t)pr.x * 128 + lane * 2);
        accx = fmaf(bf2f((ushort)v), w, accx);
        accy = fmaf(bf2f((ushort)(v >> 16)), w, accy);
    }
    *(float2*)(out + (size_t)node * 128 + lane * 2) = make_float2(accx, accy);
}

// layer-2 gather + fused log_softmax: h is bf16[n][64]; writes final output
__global__ __launch_bounds__(256)
void k_gather2(const int* __restrict__ ptr, const int2* __restrict__ csr,
               const ushort* __restrict__ h, const float* __restrict__ dinv,
               const float* __restrict__ bias, float* __restrict__ out, int n)
{
    int lane = threadIdx.x & 63;
    int node = (blockIdx.x * 256 + threadIdx.x) >> 6;
    if (node >= n) return;
    int p0 = ptr[node], p1 = ptr[node + 1];
    float di = dinv[node];
    float s  = di * di;
    float acc = fmaf(bf2f(h[(size_t)node * 64 + lane]), s, bias[lane]);
#pragma unroll 4
    for (int j = p0; j < p1; ++j) {
        int2 pr = csr[j];
        float w = __int_as_float(pr.y);
        acc = fmaf(bf2f(h[(size_t)pr.x * 64 + lane]), w, acc);
    }
    float m = acc;
#pragma unroll
    for (int off = 32; off > 0; off >>= 1) m = fmaxf(m, __shfl_xor(m, off, 64));
    float ex = expf(acc - m);
    float sum = ex;
#pragma unroll
    for (int off = 32; off > 0; off >>= 1) sum += __shfl_xor(sum, off, 64);
    out[(size_t)node * 64 + lane] = acc - m - logf(sum);
}

// per-feature sum & sumsq over nodes (128 feats)
__global__ __launch_bounds__(256)
void k_bn_stats(const float* __restrict__ a, float* __restrict__ sums,
                float* __restrict__ sumsq, int n)
{
    int f = threadIdx.x & 127;
    int r0 = blockIdx.x * 2 + (threadIdx.x >> 7);
    float s = 0.f, q = 0.f;
    for (int r = r0; r < n; r += gridDim.x * 2) {
        float v = a[(size_t)r * 128 + f];
        s += v; q += v * v;
    }
    __shared__ float ls[256], lq[256];
    ls[threadIdx.x] = s; lq[threadIdx.x] = q;
    __syncthreads();
    if (threadIdx.x < 128) {
        atomAddF(&sums[f],  ls[threadIdx.x] + ls[threadIdx.x + 128]);
        atomAddF(&sumsq[f], lq[threadIdx.x] + lq[threadIdx.x + 128]);
    }
}

__global__ void k_bn_final(const float* __restrict__ bn, const float* __restrict__ gamma,
                           const float* __restrict__ beta, float* __restrict__ scale,
                           float* __restrict__ shift, int n)
{
    int f = threadIdx.x;
    if (f < 128) {
        float inv_n = 1.0f / (float)n;
        float mu  = bn[f] * inv_n;
        float var = bn[128 + f] * inv_n - mu * mu;
        float rstd = rsqrtf(var + 1e-5f);
        float sc = gamma[f] * rstd;
        scale[f] = sc;
        shift[f] = beta[f] - mu * sc;
    }
}

extern "C" void kernel_launch(void* const* d_in, const int* in_sizes, int n_in,
                              void* d_out, int out_size, void* d_ws, size_t ws_size,
                              hipStream_t stream)
{
    const float* x     = (const float*)d_in[0];
    const int*   ei    = (const int*)  d_in[1];
    const float* ew    = (const float*)d_in[2];
    const float* W1    = (const float*)d_in[3];
    const float* b1    = (const float*)d_in[4];
    const float* gamma = (const float*)d_in[5];
    const float* beta  = (const float*)d_in[6];
    const float* W2    = (const float*)d_in[7];
    const float* b2    = (const float*)d_in[8];

    const int n = in_sizes[0] / 128;   // 100000
    const int e = in_sizes[2];         // 1600000
    const int* row = ei;               // edge_index[0]  (source)
    const int* col = ei + e;           // edge_index[1]  (target)

    // workspace layout (4-byte units):
    // dinv[n] | h1 bf16[n*128] (h2 bf16[n*64] aliases) | agg1 f32[n*128]
    // (rank aliases) | bn[256] | scale[128] | shift[128] | cnt[n] | ptr[n+1] |
    // bsum[1024] | w1f[8192 f32 = 2048 uint4] | w2f[4096 f32 = 1024 uint4] |
    // csr[e] (int2)
    float* ws    = (float*)d_ws;
    size_t off   = 0;
    float* dinv  = ws + off; off += n;
    ushort* h1   = (ushort*)(ws + off); off += (size_t)n * 64;  // n*128 bf16
    float* agg1  = ws + off; off += (size_t)n * 128;
    float* bn    = ws + off; off += 256;
    float* scale = ws + off; off += 128;
    float* shift = ws + off; off += 128;
    int*   cnt   = (int*)(ws + off); off += n;
    int*   ptr   = (int*)(ws + off); off += (size_t)(n + 1);
    int*   bsum  = (int*)(ws + off); off += 1024;
    off = (off + 3) & ~(size_t)3;       // 16-byte align for uint4
    uint4* w1f   = (uint4*)(ws + off); off += 8192;  // 128*128 bf16 = 2048 uint4
    uint4* w2f   = (uint4*)(ws + off); off += 4096;  // 128*64  bf16 = 1024 uint4
    int2*  csr   = (int2*)(ws + off);
    int*   rank  = (int*)agg1;          // agg1 dead until k_gather1
    ushort* h2   = h1;                  // h1 dead after k_gather1
    float* outp  = (float*)d_out;

    const int nb_n = (n + 255) / 256;
    const int nb_e = (e + 255) / 256;
    const int nb_wpn = (n + 3) / 4;     // wave-per-node: n*64 threads
    const int nb_qpn = (n + 15) / 16;   // 16-lane-group-per-node
    const int nb_mf  = (n + 63) / 64;   // MFMA gemm: 64 rows/block
    const int nblk_scan = (n + 1023) / 1024;

    // W fragment swizzle (no deps)
    k_wfrag<<<8, 256, 0, stream>>>(W1, w1f, 128);
    k_wfrag<<<4, 256, 0, stream>>>(W2, w2f, 64);

    // CSR build: count(+rank) -> scan -> fill -> degsum -> nrm
    k_init<<<nb_n, 256, 0, stream>>>(cnt, bn, n);
    k_cnt<<<nb_e, 256, 0, stream>>>(col, cnt, rank, e);
    k_scanA<<<nblk_scan, 256, 0, stream>>>(cnt, bsum, n);
    k_scanB<<<1, 64, 0, stream>>>(bsum, ptr, nblk_scan, n);
    k_scanC<<<nblk_scan, 256, 0, stream>>>(cnt, bsum, ptr, n);
    k_fill<<<nb_e, 256, 0, stream>>>(row, col, ew, rank, ptr, csr, e);
    k_degsum<<<nb_qpn, 256, 0, stream>>>(ptr, csr, dinv, n);
    k_nrm<<<nb_qpn, 256, 0, stream>>>(ptr, csr, dinv, n);

    // ---- layer 1: h1 = x @ W1 (bf16, MFMA) ; agg1 = gather(h1) + b1 ----
    k_mfma<128, false><<<nb_mf, 256, 0, stream>>>(x, w1f, nullptr, nullptr, h1, n);
    k_gather1<<<nb_wpn, 256, 0, stream>>>(ptr, csr, h1, dinv, b1, agg1, n);

    // ---- batchnorm stats -> scale/shift ----
    k_bn_stats<<<256, 256, 0, stream>>>(agg1, bn, bn + 128, n);
    k_bn_final<<<1, 128, 0, stream>>>(bn, gamma, beta, scale, shift, n);

    // ---- layer 2: h2 = relu(bn(agg1)) @ W2 (bf16, MFMA) ; out + lsm ----
    k_mfma<64, true><<<nb_mf, 256, 0, stream>>>(agg1, w2f, scale, shift, h2, n);
    k_gather2<<<nb_wpn, 256, 0, stream>>>(ptr, csr, h2, dinv, b2, outp, n);
}